// Round 4
// baseline (465.811 us; speedup 1.0000x reference)
//
#include <hip/hip_runtime.h>
#include <math.h>

#define D 2048
#define E 64
#define NW 8                  // waves per block; each owns a 256-wide K-chunk
#define THREADS (NW * 64)
#define KCH (D / NW)          // 256
#define NST (KCH / 4)         // 64 pipeline stages of 4 k each

// ---------------- K-loop helpers: direct global->register, no LDS ----------
__device__ __forceinline__ void load_x(float4 (&A)[8],
                                       const float* const (&xb)[8], int s) {
#pragma unroll
    for (int t = 0; t < 8; ++t)
        A[t] = *(const float4*)(xb[t] + s * 4);
}

__device__ __forceinline__ void load_w(float4 (&B)[4][2], const float* wb, int s) {
#pragma unroll
    for (int kj = 0; kj < 4; ++kj)
#pragma unroll
        for (int h = 0; h < 2; ++h)
            B[kj][h] = *(const float4*)(wb + (s * 4 + kj) * E + h * 4);
}

__device__ __forceinline__ void comp(float4 (&acc)[8][2], const float4 (&A)[8],
                                     const float4 (&B)[4][2]) {
#pragma unroll
    for (int t = 0; t < 8; ++t) {
#pragma unroll
        for (int kj = 0; kj < 4; ++kj) {
            const float av = kj == 0 ? A[t].x : kj == 1 ? A[t].y
                           : kj == 2 ? A[t].z : A[t].w;
            acc[t][0].x = fmaf(av, B[kj][0].x, acc[t][0].x);
            acc[t][0].y = fmaf(av, B[kj][0].y, acc[t][0].y);
            acc[t][0].z = fmaf(av, B[kj][0].z, acc[t][0].z);
            acc[t][0].w = fmaf(av, B[kj][0].w, acc[t][0].w);
            acc[t][1].x = fmaf(av, B[kj][1].x, acc[t][1].x);
            acc[t][1].y = fmaf(av, B[kj][1].y, acc[t][1].y);
            acc[t][1].z = fmaf(av, B[kj][1].z, acc[t][1].z);
            acc[t][1].w = fmaf(av, B[kj][1].w, acc[t][1].w);
        }
    }
}

// ---------------- reduction-tree helpers -----------------------------------
// Column groups XOR-swizzled by row&7 so the 8 tr-lanes of a fixed (ec,h)
// hit distinct bank groups (row stride 64 floats is 0 mod 32 banks).
// Any bijection is correct as long as write and add use the SAME mapping.
__device__ __forceinline__ void tile_write(float* base, const float4 (&acc)[8][2],
                                           int tr, int ec) {
    const int g = ec ^ tr;
#pragma unroll
    for (int t = 0; t < 8; ++t)
#pragma unroll
        for (int h = 0; h < 2; ++h)
            *(float4*)(base + (tr + 8 * t) * 64 + g * 8 + h * 4) = acc[t][h];
}

__device__ __forceinline__ void tile_add(const float* base, float4 (&acc)[8][2],
                                         int tr, int ec) {
    const int g = ec ^ tr;
#pragma unroll
    for (int t = 0; t < 8; ++t)
#pragma unroll
        for (int h = 0; h < 2; ++h) {
            float4 v = *(const float4*)(base + (tr + 8 * t) * 64 + g * 8 + h * 4);
            acc[t][h].x += v.x; acc[t][h].y += v.y;
            acc[t][h].z += v.z; acc[t][h].w += v.w;
        }
}

__global__ __launch_bounds__(THREADS, 2)
void gating_kernel(const float* __restrict__ x,
                   const float* __restrict__ W,
                   const float* __restrict__ Bv,
                   float* __restrict__ out)
{
    // LDS layout (64 KB, regions disjoint at time of use):
    //   bytes [    0, 16384): tree tile 0      (live through final add)
    //   bytes [16384, 65536): tree tiles 1..3  (dead after tree stage 4)
    //   bytes [20480, 37120): logits [64][65]  (written at final stage only)
    //   bytes [37120, 38144): sw1/sw2/si1/si2  (written at final stage only)
    __shared__ __align__(16) char smem[65536];

    const int tid  = threadIdx.x;
    const int lane = tid & 63;
    const int w    = tid >> 6;
    const int tok0 = blockIdx.x * 64;
    const int tr = lane & 7;     // token row 0..7 (lane grid 8x8)
    const int ec = lane >> 3;    // expert column group (8 experts each)

    // per-lane base pointers
    const float* xb[8];
#pragma unroll
    for (int t = 0; t < 8; ++t)
        xb[t] = x + (size_t)(tok0 + tr + 8 * t) * D + w * KCH;
    const float* wb = W + (size_t)(w * KCH) * E + ec * 8;

    float4 acc[8][2];
#pragma unroll
    for (int t = 0; t < 8; ++t) {
        acc[t][0] = float4{0.f, 0.f, 0.f, 0.f};
        acc[t][1] = float4{0.f, 0.f, 0.f, 0.f};
    }

    // ---- K-loop: 2-stage register pipeline, no LDS, no barriers ----
    float4 A0[8], A1[8], B0[4][2], B1[4][2];
    load_x(A0, xb, 0);
    load_w(B0, wb, 0);
#pragma unroll 1
    for (int s = 0; s < NST; s += 2) {
        load_x(A1, xb, s + 1);
        load_w(B1, wb, s + 1);
        comp(acc, A0, B0);
        if (s + 2 < NST) {
            load_x(A0, xb, s + 2);
            load_w(B0, wb, s + 2);
        }
        comp(acc, A1, B1);
    }

    // ---- cross-wave K-reduction: 3-level tree over 4 LDS tiles ----
    float* red = (float*)smem;
    __syncthreads();
    if (w >= 4) tile_write(red + (size_t)(w - 4) * 4096, acc, tr, ec);
    __syncthreads();
    if (w < 4)  tile_add(red + (size_t)w * 4096, acc, tr, ec);   // w0+=w4 etc.
    __syncthreads();
    if (w == 2 || w == 3) tile_write(red + (size_t)(w - 2) * 4096, acc, tr, ec);
    __syncthreads();
    if (w < 2) tile_add(red + (size_t)w * 4096, acc, tr, ec);    // w0+=w2+w6 etc.
    __syncthreads();
    if (w == 1) tile_write(red, acc, tr, ec);
    __syncthreads();

    float* logits = (float*)(smem + 20480);        // [64][65]
    float* sw1 = (float*)(smem + 37120);
    float* sw2 = (float*)(smem + 37376);
    int*   si1 = (int*)  (smem + 37632);
    int*   si2 = (int*)  (smem + 37888);

    if (w == 0) {
        tile_add(red, acc, tr, ec);                // full 8-way sum
#pragma unroll
        for (int t = 0; t < 8; ++t) {
            int row = tr + 8 * t;
#pragma unroll
            for (int h = 0; h < 2; ++h) {
                logits[row * 65 + ec * 8 + h * 4 + 0] = acc[t][h].x;
                logits[row * 65 + ec * 8 + h * 4 + 1] = acc[t][h].y;
                logits[row * 65 + ec * 8 + h * 4 + 2] = acc[t][h].z;
                logits[row * 65 + ec * 8 + h * 4 + 3] = acc[t][h].w;
            }
        }
        // lane = token: top-2 scan (+bias). Strict '>' matches top_k tie order.
        float m1 = -3.4e38f, m2 = -3.4e38f;
        int i1 = 0, i2 = 0;
#pragma unroll
        for (int e = 0; e < E; ++e) {
            float v = logits[lane * 65 + e] + Bv[e];
            if (v > m1)      { m2 = m1; i2 = i1; m1 = v; i1 = e; }
            else if (v > m2) { m2 = v; i2 = e; }
        }
        float p = 1.0f / (1.0f + expf(m2 - m1));   // stable: m2 <= m1
        sw1[lane] = p; sw2[lane] = 1.0f - p;
        si1[lane] = i1; si2[lane] = i2;
    }
    __syncthreads();

    // ---- coalesced float4 store of the 64x64 tile ----
    float4* o4 = (float4*)(out + (size_t)tok0 * E);
#pragma unroll
    for (int r = 0; r < 2; ++r) {
        int idx = r * THREADS + tid;        // 0..1023 float4s
        int tl  = idx >> 4;                 // token 0..63
        int e0  = (idx & 15) * 4;
        int a1 = si1[tl], a2 = si2[tl];
        float v1 = sw1[tl], v2 = sw2[tl];
        float4 v;
        v.x = (e0 + 0 == a1) ? v1 : (e0 + 0 == a2) ? v2 : 0.0f;
        v.y = (e0 + 1 == a1) ? v1 : (e0 + 1 == a2) ? v2 : 0.0f;
        v.z = (e0 + 2 == a1) ? v1 : (e0 + 2 == a2) ? v2 : 0.0f;
        v.w = (e0 + 3 == a1) ? v1 : (e0 + 3 == a2) ? v2 : 0.0f;
        o4[idx] = v;
    }
}

extern "C" void kernel_launch(void* const* d_in, const int* in_sizes, int n_in,
                              void* d_out, int out_size, void* d_ws, size_t ws_size,
                              hipStream_t stream) {
    const float* x = (const float*)d_in[0];
    const float* W = (const float*)d_in[1];
    const float* b = (const float*)d_in[2];
    float* out = (float*)d_out;

    const int tokens = in_sizes[0] / D;      // 16384
    const int blocks = tokens / 64;          // 256

    gating_kernel<<<blocks, THREADS, 0, stream>>>(x, W, b, out);
}

// Round 5
// 289.854 us; speedup vs baseline: 1.6071x; 1.6071x over previous
//
#include <hip/hip_runtime.h>
#include <math.h>

#define D 2048
#define E 64
#define NW 8                  // waves per block; each owns a K-chunk
#define THREADS (NW * 64)
#define TOK 32                // tokens per block
#define KCH (D / NW)          // 256
#define BK 4                  // k per staged W tile
#define NIT (KCH / BK)        // 64

// LDS map (bytes):
//  [0, 16384)    : per-wave W staging, wave w at w*2048 (two 1KB buffers)
//  [0, 32768)    : reduction tiles 0..3 (8KB each) -- used after K-loop barrier
//  [32768, 41088): logits [32][65]
//  [41088, 41600): sw1, sw2, si1, si2
#define SMEM_BYTES 41728

// ---- helpers ---------------------------------------------------------------
__device__ __forceinline__ void load_x(float4 (&A)[4],
                                       const float* const (&xb)[4], int it) {
#pragma unroll
    for (int t = 0; t < 4; ++t)
        A[t] = *(const float4*)(xb[t] + it * BK);
}

// 32 FMAs per kj; A[t] holds k-values [it*4 .. it*4+3] for token row t.
__device__ __forceinline__ void compute(float4 (&acc)[4][2], const float4 (&A)[4],
                                        const float* bt, int ec) {
#pragma unroll
    for (int kj = 0; kj < 4; ++kj) {
        float4 b0 = *(const float4*)(bt + kj * E + ec * 8);
        float4 b1 = *(const float4*)(bt + kj * E + ec * 8 + 4);
#pragma unroll
        for (int t = 0; t < 4; ++t) {
            const float av = kj == 0 ? A[t].x : kj == 1 ? A[t].y
                           : kj == 2 ? A[t].z : A[t].w;
            acc[t][0].x = fmaf(av, b0.x, acc[t][0].x);
            acc[t][0].y = fmaf(av, b0.y, acc[t][0].y);
            acc[t][0].z = fmaf(av, b0.z, acc[t][0].z);
            acc[t][0].w = fmaf(av, b0.w, acc[t][0].w);
            acc[t][1].x = fmaf(av, b1.x, acc[t][1].x);
            acc[t][1].y = fmaf(av, b1.y, acc[t][1].y);
            acc[t][1].z = fmaf(av, b1.z, acc[t][1].z);
            acc[t][1].w = fmaf(av, b1.w, acc[t][1].w);
        }
    }
}

// Reduction-tree fragment IO. g = ec^tr is a bijection per row; correct as long
// as write and add use the same mapping (spreads bank groups as a bonus).
__device__ __forceinline__ void tile_write(float* base, const float4 (&acc)[4][2],
                                           int tr, int ec) {
    const int g = ec ^ tr;
#pragma unroll
    for (int t = 0; t < 4; ++t)
#pragma unroll
        for (int h = 0; h < 2; ++h)
            *(float4*)(base + (tr + 8 * t) * 64 + g * 8 + h * 4) = acc[t][h];
}

__device__ __forceinline__ void tile_add(const float* base, float4 (&acc)[4][2],
                                         int tr, int ec) {
    const int g = ec ^ tr;
#pragma unroll
    for (int t = 0; t < 4; ++t)
#pragma unroll
        for (int h = 0; h < 2; ++h) {
            float4 v = *(const float4*)(base + (tr + 8 * t) * 64 + g * 8 + h * 4);
            acc[t][h].x += v.x; acc[t][h].y += v.y;
            acc[t][h].z += v.z; acc[t][h].w += v.w;
        }
}

__global__ __launch_bounds__(THREADS, 2)
void gating_kernel(const float* __restrict__ x,
                   const float* __restrict__ W,
                   const float* __restrict__ Bv,
                   float* __restrict__ out)
{
    __shared__ __align__(16) char smem[SMEM_BYTES];

    const int tid  = threadIdx.x;
    const int lane = tid & 63;
    const int w    = tid >> 6;
    const int tok0 = blockIdx.x * TOK;
    const int tr = lane & 7;     // token row 0..7  (lane grid 8x8)
    const int ec = lane >> 3;    // expert column group (8 experts each)

    // per-lane x row base pointers (rows tr, tr+8, tr+16, tr+24)
    const float* xb[4];
#pragma unroll
    for (int t = 0; t < 4; ++t)
        xb[t] = x + (size_t)(tok0 + tr + 8 * t) * D + w * KCH;

    // W staging: tile it = rows [w*KCH + it*BK, +BK) x 64 cols = 1KB contiguous.
    // Lane loads float4 at lane*16B, ds_writes to same offset (linear layout).
    const float* wgl = W + (size_t)(w * KCH) * E + lane * 4;
    float* wlds = (float*)(smem + w * 2048);          // buf0; buf1 = +256 floats

    float4 acc[4][2];
#pragma unroll
    for (int t = 0; t < 4; ++t) {
        acc[t][0] = float4{0.f, 0.f, 0.f, 0.f};
        acc[t][1] = float4{0.f, 0.f, 0.f, 0.f};
    }

    // ---- prologue: stage tile 0, prefetch tile 1 ----
    float4 wr0 = *(const float4*)(wgl);               // tile 0
    *(float4*)(wlds + lane * 4) = wr0;
    float4 wr1 = *(const float4*)(wgl + BK * E);      // tile 1
    float4 A0[4], A1[4];
    load_x(A0, xb, 0);

    // ---- K-loop: wave-private, no barriers. Same-wave DS ops execute in
    // order, so single-wave WAR on the two buffers is safe; the compiler
    // tracks the ds_write->ds_read data dependency via lgkmcnt. ----
#pragma unroll 1
    for (int it = 0; it < NIT; it += 2) {
        // stage tile it+1 into buf1; prefetch tile it+2; prefetch x(it+1)
        *(float4*)(wlds + 256 + lane * 4) = wr1;
        if (it + 2 < NIT) wr0 = *(const float4*)(wgl + (it + 2) * BK * E);
        load_x(A1, xb, it + 1);
        compute(acc, A0, wlds, ec);                   // tile it (buf0)

        if (it + 2 < NIT) {
            *(float4*)(wlds + lane * 4) = wr0;        // stage tile it+2 -> buf0
            if (it + 3 < NIT) wr1 = *(const float4*)(wgl + (it + 3) * BK * E);
            load_x(A0, xb, it + 2);
        }
        compute(acc, A1, wlds + 256, ec);             // tile it+1 (buf1)
    }

    // ---- cross-wave K-reduction: 3-level tree over 4 LDS tiles ----
    float* red = (float*)smem;
    __syncthreads();
    if (w >= 4) tile_write(red + (size_t)(w - 4) * 2048, acc, tr, ec);
    __syncthreads();
    if (w < 4)  tile_add(red + (size_t)w * 2048, acc, tr, ec);
    __syncthreads();
    if (w == 2 || w == 3) tile_write(red + (size_t)(w - 2) * 2048, acc, tr, ec);
    __syncthreads();
    if (w < 2) tile_add(red + (size_t)w * 2048, acc, tr, ec);
    __syncthreads();
    if (w == 1) tile_write(red, acc, tr, ec);
    __syncthreads();

    float* logits = (float*)(smem + 32768);           // [32][65]
    float* sw1 = (float*)(smem + 41088);
    float* sw2 = (float*)(smem + 41216);
    int*   si1 = (int*)  (smem + 41344);
    int*   si2 = (int*)  (smem + 41472);

    if (w == 0) {
        tile_add(red, acc, tr, ec);                   // full 8-way K sum
#pragma unroll
        for (int t = 0; t < 4; ++t) {
            int row = tr + 8 * t;
#pragma unroll
            for (int h = 0; h < 2; ++h) {
                logits[row * 65 + ec * 8 + h * 4 + 0] = acc[t][h].x;
                logits[row * 65 + ec * 8 + h * 4 + 1] = acc[t][h].y;
                logits[row * 65 + ec * 8 + h * 4 + 2] = acc[t][h].z;
                logits[row * 65 + ec * 8 + h * 4 + 3] = acc[t][h].w;
            }
        }
    }
    __syncthreads();
    if (w == 0 && lane < TOK) {
        // lane = token: top-2 scan (+bias). Strict '>' matches top_k tie order.
        float m1 = -3.4e38f, m2 = -3.4e38f;
        int i1 = 0, i2 = 0;
#pragma unroll
        for (int e = 0; e < E; ++e) {
            float v = logits[lane * 65 + e] + Bv[e];
            if (v > m1)      { m2 = m1; i2 = i1; m1 = v; i1 = e; }
            else if (v > m2) { m2 = v; i2 = e; }
        }
        float p = 1.0f / (1.0f + expf(m2 - m1));      // stable: m2 <= m1
        sw1[lane] = p; sw2[lane] = 1.0f - p;
        si1[lane] = i1; si2[lane] = i2;
    }
    __syncthreads();

    // ---- coalesced float4 store of the 32x64 tile (512 float4 = THREADS) ----
    float4* o4 = (float4*)(out + (size_t)tok0 * E);
    {
        int idx = tid;                  // 0..511
        int tl  = idx >> 4;             // token 0..31
        int e0  = (idx & 15) * 4;
        int a1 = si1[tl], a2 = si2[tl];
        float v1 = sw1[tl], v2 = sw2[tl];
        float4 v;
        v.x = (e0 + 0 == a1) ? v1 : (e0 + 0 == a2) ? v2 : 0.0f;
        v.y = (e0 + 1 == a1) ? v1 : (e0 + 1 == a2) ? v2 : 0.0f;
        v.z = (e0 + 2 == a1) ? v1 : (e0 + 2 == a2) ? v2 : 0.0f;
        v.w = (e0 + 3 == a1) ? v1 : (e0 + 3 == a2) ? v2 : 0.0f;
        o4[idx] = v;
    }
}

extern "C" void kernel_launch(void* const* d_in, const int* in_sizes, int n_in,
                              void* d_out, int out_size, void* d_ws, size_t ws_size,
                              hipStream_t stream) {
    const float* x = (const float*)d_in[0];
    const float* W = (const float*)d_in[1];
    const float* b = (const float*)d_in[2];
    float* out = (float*)d_out;

    const int tokens = in_sizes[0] / D;      // 16384
    const int blocks = tokens / TOK;         // 512

    gating_kernel<<<blocks, THREADS, 0, stream>>>(x, W, b, out);
}

// Round 6
// 259.340 us; speedup vs baseline: 1.7961x; 1.1177x over previous
//
#include <hip/hip_runtime.h>
#include <math.h>

#define D 2048
#define E 64
#define EH 32                 // experts per wave (half)
#define TOK 64                // tokens per block (lane = token)
#define THREADS 1024          // 16 waves = 8 K-chunks x 2 expert halves
#define NKC 8
#define KCH (D / NKC)         // 256

typedef float f16v __attribute__((ext_vector_type(16)));

// W row slice (32 floats) from a wave-uniform address -> s_load_dwordx16 x2.
__device__ __forceinline__ void wload(f16v (&dst)[2], const float* p) {
    dst[0] = *(const f16v*)(p);
    dst[1] = *(const f16v*)(p + 16);
}

// 32 FMAs: acc[e] += xj * wb[e]  (wb in SGPRs -> v_fmac_f32 v, s, v)
__device__ __forceinline__ void fmagrp(float (&acc)[EH], float xj,
                                       const f16v (&wb)[2]) {
#pragma unroll
    for (int h = 0; h < 2; ++h)
#pragma unroll
        for (int i = 0; i < 16; ++i)
            acc[h * 16 + i] = fmaf(xj, wb[h][i], acc[h * 16 + i]);
}

// Reduction-tile IO. Tile = [64 tokens][32 floats]; lane owns its row.
// Column-slot swizzle (c+lane)&7 spreads b128 ops over all 32 banks.
// acc is always indexed by the compile-time c (runtime only in the address).
__device__ __forceinline__ void tile_write(float* base, const float (&acc)[EH],
                                           int lane) {
#pragma unroll
    for (int c = 0; c < 8; ++c) {
        int s = (c + lane) & 7;
        float4 v = {acc[4 * c], acc[4 * c + 1], acc[4 * c + 2], acc[4 * c + 3]};
        *(float4*)(base + lane * EH + s * 4) = v;
    }
}

__device__ __forceinline__ void tile_add(const float* base, float (&acc)[EH],
                                         int lane) {
#pragma unroll
    for (int c = 0; c < 8; ++c) {
        int s = (c + lane) & 7;
        float4 v = *(const float4*)(base + lane * EH + s * 4);
        acc[4 * c] += v.x; acc[4 * c + 1] += v.y;
        acc[4 * c + 2] += v.z; acc[4 * c + 3] += v.w;
    }
}

__global__ __launch_bounds__(THREADS, 4)
void gating_kernel(const float* __restrict__ x,
                   const float* __restrict__ W,
                   const float* __restrict__ Bv,
                   float* __restrict__ out)
{
    // LDS (64 KB): tree tiles 0..7 at w*8KB. After the final tree barrier,
    // tiles 0..1 area is reused for logits [64][65] and the top-2 arrays.
    __shared__ __align__(16) char smem[65536];

    const int tid  = threadIdx.x;
    const int lane = tid & 63;
    const int w    = __builtin_amdgcn_readfirstlane(tid >> 6);
    const int eh   = w & 1;          // expert half (32 experts)
    const int kc   = w >> 1;         // K-chunk 0..7
    const int tok0 = blockIdx.x * TOK;

    const float* xrow = x + (size_t)(tok0 + lane) * D + kc * KCH;  // per-lane
    const float* wk   = W + (size_t)kc * KCH * E + eh * EH;        // uniform

    float acc[EH];
#pragma unroll
    for (int e = 0; e < EH; ++e) acc[e] = 0.f;

    // ---- K-loop: B from SGPRs (2-row double buffer), x per-lane float4 ----
    f16v wb[2][2];
    wload(wb[0], wk);                 // row 0
    wload(wb[1], wk + E);             // row 1
    float4 xv = *(const float4*)(xrow);
    float4 xn = *(const float4*)(xrow + 4);

#pragma unroll 1
    for (int k4 = 0; k4 < KCH / 4; ++k4) {
        float4 xc = xv; xv = xn;
        int nx = (k4 + 2 < KCH / 4) ? k4 + 2 : KCH / 4 - 1;
        xn = *(const float4*)(xrow + nx * 4);
#pragma unroll
        for (int j = 0; j < 4; ++j) {
            const float xj = j == 0 ? xc.x : j == 1 ? xc.y
                           : j == 2 ? xc.z : xc.w;
            fmagrp(acc, xj, wb[j & 1]);        // uses row 4*k4+j
            int r = 4 * k4 + j + 2;            // prefetch 2 rows ahead
            if (r > KCH - 1) r = KCH - 1;
            wload(wb[j & 1], wk + (size_t)r * E);
        }
    }

    // ---- cross-wave K-reduction: 3-level tree, pairing (kc, kc+step) ----
    float* tiles = (float*)smem;               // tile i at i*2048 floats
    __syncthreads();
    if (w >= 8) tile_write(tiles + (w - 8) * 2048, acc, lane);
    __syncthreads();
    if (w < 8)  tile_add(tiles + w * 2048, acc, lane);
    __syncthreads();
    if (w >= 4 && w < 8) tile_write(tiles + (w - 4) * 2048, acc, lane);
    __syncthreads();
    if (w < 4)  tile_add(tiles + w * 2048, acc, lane);
    __syncthreads();
    if (w == 2 || w == 3) tile_write(tiles + (w - 2) * 2048, acc, lane);
    __syncthreads();
    if (w < 2)  tile_add(tiles + w * 2048, acc, lane);   // w0: eh0, w1: eh1 full
    __syncthreads();                                     // tiles now dead

    float* logits = (float*)smem;              // [64][65]
    float* sw1 = (float*)(smem + 16640);
    float* sw2 = (float*)(smem + 16896);
    int*   si1 = (int*)  (smem + 17152);
    int*   si2 = (int*)  (smem + 17408);

    if (w < 2) {                               // write full logits tile
#pragma unroll
        for (int e = 0; e < EH; ++e)
            logits[lane * 65 + eh * EH + e] = acc[e];
    }
    __syncthreads();

    if (w == 0) {
        // lane = token: top-2 scan (+bias). Strict '>' matches top_k ties.
        float m1 = -3.4e38f, m2 = -3.4e38f;
        int i1 = 0, i2 = 0;
#pragma unroll
        for (int e = 0; e < E; ++e) {
            float v = logits[lane * 65 + e] + Bv[e];
            if (v > m1)      { m2 = m1; i2 = i1; m1 = v; i1 = e; }
            else if (v > m2) { m2 = v; i2 = e; }
        }
        float p = 1.0f / (1.0f + expf(m2 - m1));   // stable: m2 <= m1
        sw1[lane] = p; sw2[lane] = 1.0f - p;
        si1[lane] = i1; si2[lane] = i2;
    }
    __syncthreads();

    // ---- coalesced float4 store of the 64x64 tile (1024 float4) ----
    float4* o4 = (float4*)(out + (size_t)tok0 * E);
    {
        int idx = tid;                  // 0..1023
        int tl  = idx >> 4;             // token 0..63
        int e0  = (idx & 15) * 4;
        int a1 = si1[tl], a2 = si2[tl];
        float v1 = sw1[tl], v2 = sw2[tl];
        float4 v;
        v.x = (e0 + 0 == a1) ? v1 : (e0 + 0 == a2) ? v2 : 0.0f;
        v.y = (e0 + 1 == a1) ? v1 : (e0 + 1 == a2) ? v2 : 0.0f;
        v.z = (e0 + 2 == a1) ? v1 : (e0 + 2 == a2) ? v2 : 0.0f;
        v.w = (e0 + 3 == a1) ? v1 : (e0 + 3 == a2) ? v2 : 0.0f;
        o4[idx] = v;
    }
}

extern "C" void kernel_launch(void* const* d_in, const int* in_sizes, int n_in,
                              void* d_out, int out_size, void* d_ws, size_t ws_size,
                              hipStream_t stream) {
    const float* x = (const float*)d_in[0];
    const float* W = (const float*)d_in[1];
    const float* b = (const float*)d_in[2];
    float* out = (float*)d_out;

    const int tokens = in_sizes[0] / D;      // 16384
    const int blocks = tokens / TOK;         // 256

    gating_kernel<<<blocks, THREADS, 0, stream>>>(x, W, b, out);
}